// Round 7
// baseline (350.816 us; speedup 1.0000x reference)
//
#include <hip/hip_runtime.h>
#include <hip/hip_fp16.h>

// Involution (B=16,C=256,H=W=56,K=7,G=16,CR=64).
// R7: de-fuse K3. k3a = pure MFMA span GEMM (BN+ReLU+split fused in, r as
// B-operand / w2 as A-operand -> D=[tap][px]) writing ker fp16 to ws;
// k3b = pure involution (d-pair fp16 halo in swizzled LDS, fma_mix inner).
// ker buffer chunked adaptively by ws_size (c b's at a time, c in {16,8,4,2}).

namespace {
constexpr int Bn = 16, Cn = 256, Hn = 56, Wn = 56, Gn = 16, CRn = 64;
constexpr int HWn = Hn * Wn;          // 3136
constexpr int NPIX = Bn * HWn;        // 50176
constexpr int K1B = NPIX / 64;        // 784
constexpr float EPSc = 1e-5f;

constexpr size_t RT_OFF    = 0;                                 // fp32 [NPIX][64]
constexpr size_t PART_OFF  = RT_OFF + (size_t)NPIX * 64 * 4;    // fp32 [784][128]
constexpr size_t PART2_OFF = PART_OFF + (size_t)K1B * 128 * 4;  // fp32 [16][128]
constexpr size_t AB_OFF    = PART2_OFF + 16 * 128 * 4;          // fp32 [128]
constexpr size_t W1H_OFF   = AB_OFF + 512;                      // u16 [64][256]
constexpr size_t W1L_OFF   = W1H_OFF + (size_t)64 * 256 * 2;
constexpr size_t W2H_OFF   = W1L_OFF + (size_t)64 * 256 * 2;    // u16 [16][64][64]
constexpr size_t W2L_OFF   = W2H_OFF + (size_t)16 * 64 * 64 * 2;
constexpr size_t KER_OFF   = W2L_OFF + (size_t)16 * 64 * 64 * 2;
constexpr size_t KERB      = (size_t)16 * 49 * HWn * 2;         // per-b: 4.92 MB
} // namespace

using f32x4  = __attribute__((ext_vector_type(4))) float;
using bf16x8 = __attribute__((ext_vector_type(8))) short;

__device__ __forceinline__ unsigned short f2bf(float f) {   // RNE fp32->bf16
    unsigned u = __float_as_uint(f);
    return (unsigned short)((u + 0x7fffu + ((u >> 16) & 1u)) >> 16);
}
__device__ __forceinline__ float bf2f(unsigned short h) {
    return __uint_as_float(((unsigned)h) << 16);
}
__device__ __forceinline__ void split2(float v, unsigned short& h, unsigned short& l) {
    h = f2bf(v);
    l = f2bf(v - bf2f(h));
}
__device__ __forceinline__ unsigned short f2h(float f) {
    __half h = __float2half(f);
    return *reinterpret_cast<unsigned short*>(&h);
}
__device__ __forceinline__ float h2f(unsigned short u) {
    __half h = *reinterpret_cast<__half*>(&u);
    return __half2float(h);
}
__device__ __forceinline__ f32x4 MFMA(bf16x8 a, bf16x8 b, f32x4 c) {
    return __builtin_amdgcn_mfma_f32_16x16x32_bf16(a, b, c, 0, 0, 0);
}

// ---------------------------------------------------------------------------
// K0: w1 -> bf16 hi/lo [o][c]; w2 -> bf16 hi/lo [g][tap(64,zero-pad)][cr]
// ---------------------------------------------------------------------------
__global__ __launch_bounds__(256) void k0_prep(
    const float* __restrict__ w1, const float* __restrict__ w2,
    unsigned short* __restrict__ w1h, unsigned short* __restrict__ w1l,
    unsigned short* __restrict__ w2h, unsigned short* __restrict__ w2l)
{
    const int i = blockIdx.x * 256 + threadIdx.x;
    if (i < 64 * 256) {
        unsigned short h, l;
        split2(w1[i], h, l);
        w1h[i] = h; w1l[i] = l;
    }
    const int j = i - 64 * 256;
    if (j >= 0 && j < 16 * 64 * 64) {
        const int cr = j & 63, tap = (j >> 6) & 63, g = j >> 12;
        const float v = (tap < 49) ? w2[(size_t)(tap * Gn + g) * CRn + cr] : 0.f;
        unsigned short h, l;
        split2(v, h, l);
        w2h[j] = h; w2l[j] = l;
    }
}

// ---------------------------------------------------------------------------
// K1: rT[px][o] = sum_c x[px][c]*w1[o][c], MFMA, 64px x 64o per block.
// (unchanged from verified R6)
// ---------------------------------------------------------------------------
__global__ __launch_bounds__(256) void k1_reduce(
    const float* __restrict__ x,
    const unsigned short* __restrict__ w1h, const unsigned short* __restrict__ w1l,
    float* __restrict__ rT, float* __restrict__ part)
{
    __shared__ unsigned xsh[64][36];
    __shared__ unsigned xsl[64][36];
    __shared__ float wps[4][64], wpq[4][64];

    const int t = threadIdx.x;
    const int wv = t >> 6, l = t & 63, lm = l & 15, lq = l >> 4;
    const int px0 = blockIdx.x * 64;

    f32x4 acc[4];
    #pragma unroll
    for (int n = 0; n < 4; ++n) acc[n] = f32x4{0.f, 0.f, 0.f, 0.f};

    for (int kc = 0; kc < 4; ++kc) {
        __syncthreads();
        #pragma unroll
        for (int it = 0; it < 8; ++it) {
            const int e = it * 256 + t;
            const int pxl = e & 63, cp = e >> 6;
            const int px = px0 + pxl;
            const int b = px / HWn, hw = px - b * HWn;
            const float* xp = x + ((size_t)b * Cn + kc * 64 + cp * 2) * HWn + hw;
            const float v0 = xp[0], v1 = xp[HWn];
            unsigned short h0, l0, h1, l1;
            split2(v0, h0, l0);
            split2(v1, h1, l1);
            const int col = cp ^ ((pxl & 7) << 2);
            xsh[pxl][col] = (unsigned)h0 | ((unsigned)h1 << 16);
            xsl[pxl][col] = (unsigned)l0 | ((unsigned)l1 << 16);
        }
        __syncthreads();

        #pragma unroll
        for (int ks = 0; ks < 2; ++ks) {
            const int pxl = wv * 16 + lm;
            const int base = (ks * 16 + lq * 4) ^ ((pxl & 7) << 2);
            const bf16x8 ah = *(const bf16x8*)&xsh[pxl][base];
            const bf16x8 al = *(const bf16x8*)&xsl[pxl][base];
            #pragma unroll
            for (int n = 0; n < 4; ++n) {
                const size_t wo = (size_t)(n * 16 + lm) * 256 + kc * 64 + ks * 32 + lq * 8;
                const bf16x8 bh = *(const bf16x8*)(w1h + wo);
                const bf16x8 bl = *(const bf16x8*)(w1l + wo);
                acc[n] = MFMA(al, bh, acc[n]);
                acc[n] = MFMA(ah, bl, acc[n]);
                acc[n] = MFMA(ah, bh, acc[n]);
            }
        }
    }

    float s[4] = {0.f, 0.f, 0.f, 0.f}, q[4] = {0.f, 0.f, 0.f, 0.f};
    #pragma unroll
    for (int n = 0; n < 4; ++n)
        #pragma unroll
        for (int i = 0; i < 4; ++i) {
            const float v = acc[n][i];
            const int px = px0 + wv * 16 + lq * 4 + i;
            rT[(size_t)px * 64 + n * 16 + lm] = v;
            s[n] += v;
            q[n] += v * v;
        }
    #pragma unroll
    for (int n = 0; n < 4; ++n) {
        s[n] += __shfl_xor(s[n], 16, 64); s[n] += __shfl_xor(s[n], 32, 64);
        q[n] += __shfl_xor(q[n], 16, 64); q[n] += __shfl_xor(q[n], 32, 64);
        if (lq == 0) { wps[wv][n * 16 + lm] = s[n]; wpq[wv][n * 16 + lm] = q[n]; }
    }
    __syncthreads();
    if (t < 128) {
        const int ch = t >> 1;
        float v;
        if (t & 1) v = (wpq[0][ch] + wpq[1][ch]) + (wpq[2][ch] + wpq[3][ch]);
        else       v = (wps[0][ch] + wps[1][ch]) + (wps[2][ch] + wps[3][ch]);
        part[(size_t)blockIdx.x * 128 + t] = v;
    }
}

// ---------------------------------------------------------------------------
__global__ __launch_bounds__(128) void k2a_fold(
    const float* __restrict__ part, float* __restrict__ part2)
{
    const int t = threadIdx.x, j = blockIdx.x;
    float s = 0.f;
    for (int c = 0; c < K1B / 16; ++c)
        s += part[(size_t)(j * (K1B / 16) + c) * 128 + t];
    part2[(size_t)j * 128 + t] = s;
}

__global__ __launch_bounds__(128) void k2_stats(
    const float* __restrict__ part2, const float* __restrict__ gamma,
    const float* __restrict__ beta, float* __restrict__ ab)
{
    const int t = threadIdx.x;
    float s = 0.f;
    #pragma unroll
    for (int j = 0; j < 16; ++j) s += part2[(size_t)j * 128 + t];
    __shared__ float L[128];
    L[t] = s;
    __syncthreads();
    if (t < 64) {
        const float inv = 1.0f / (float)NPIX;
        const float mean = L[2 * t] * inv;
        const float var = L[2 * t + 1] * inv - mean * mean;
        const float A = gamma[t] * rsqrtf(var + EPSc);
        ab[t] = A;
        ab[64 + t] = beta[t] - mean * A;
    }
}

// ---------------------------------------------------------------------------
// K3a: span GEMM -> ker fp16 [bl][g][tap(49)][px(3136)].
// Per block: 64 px of one b, 8 g's. Stage rT tile with BN+ReLU+split into
// swizzled LDS; r = B operand (col=px), w2 = A operand (row=tap).
// D col = px = lane&15 -> px-contiguous ker stores.
// ---------------------------------------------------------------------------
__global__ __launch_bounds__(256) void k3a_span(
    const float* __restrict__ rT, const float* __restrict__ ab,
    const unsigned short* __restrict__ w2h, const unsigned short* __restrict__ w2l,
    const float* __restrict__ b2, unsigned short* __restrict__ ker, int b0)
{
    __shared__ unsigned xsh[64][36];
    __shared__ unsigned xsl[64][36];

    const int t = threadIdx.x;
    const int wv = t >> 6, l = t & 63, lm = l & 15, lq = l >> 4;
    const int bl = blockIdx.y, b = b0 + bl;
    const int px0 = blockIdx.x * 64;
    const int g0 = blockIdx.z * 8;

    // stage 64px x 64cr with BN+ReLU, split to bf16 hi/lo pairs
    #pragma unroll
    for (int it = 0; it < 8; ++it) {
        const int e = it * 256 + t;
        const int cp = e & 31, pxl = e >> 5;
        const float2 v = *(const float2*)&rT[((size_t)b * HWn + px0 + pxl) * 64 + cp * 2];
        const float r0 = fmaxf(ab[cp * 2] * v.x + ab[64 + cp * 2], 0.f);
        const float r1 = fmaxf(ab[cp * 2 + 1] * v.y + ab[64 + cp * 2 + 1], 0.f);
        unsigned short h0, l0, h1, l1;
        split2(r0, h0, l0);
        split2(r1, h1, l1);
        const int col = cp ^ ((pxl & 7) << 2);
        xsh[pxl][col] = (unsigned)h0 | ((unsigned)h1 << 16);
        xsl[pxl][col] = (unsigned)l0 | ((unsigned)l1 << 16);
    }
    __syncthreads();

    // B-frags: this wave's 16 px, loaded once, reused across all 8 g
    bf16x8 bh[2], blo[2];
    #pragma unroll
    for (int ks = 0; ks < 2; ++ks) {
        const int pxl = wv * 16 + lm;
        const int base = (ks * 16 + lq * 4) ^ ((pxl & 7) << 2);
        bh[ks]  = *(const bf16x8*)&xsh[pxl][base];
        blo[ks] = *(const bf16x8*)&xsl[pxl][base];
    }

    for (int gi = 0; gi < 8; ++gi) {
        const int g = g0 + gi;
        f32x4 acc[4];
        #pragma unroll
        for (int mt = 0; mt < 4; ++mt) acc[mt] = f32x4{0.f, 0.f, 0.f, 0.f};

        #pragma unroll
        for (int ks = 0; ks < 2; ++ks)
            #pragma unroll
            for (int mt = 0; mt < 4; ++mt) {
                const size_t wo = (size_t)(g * 64 + mt * 16 + lm) * 64 + ks * 32 + lq * 8;
                const bf16x8 a_h = *(const bf16x8*)(w2h + wo);
                const bf16x8 a_l = *(const bf16x8*)(w2l + wo);
                acc[mt] = MFMA(a_l, bh[ks], acc[mt]);
                acc[mt] = MFMA(a_h, blo[ks], acc[mt]);
                acc[mt] = MFMA(a_h, bh[ks], acc[mt]);
            }

        // D: col px = lane&15, row tap = mt*16 + lq*4 + i
        unsigned short* kg = ker + ((size_t)(bl * 16 + g) * 49) * HWn + px0 + wv * 16 + lm;
        #pragma unroll
        for (int mt = 0; mt < 4; ++mt)
            #pragma unroll
            for (int i = 0; i < 4; ++i) {
                const int tap = mt * 16 + lq * 4 + i;
                if (tap < 49)
                    kg[(size_t)tap * HWn] = f2h(acc[mt][i] + b2[tap * 16 + g]);
            }
    }
}

// ---------------------------------------------------------------------------
// K3b: involution. Block = (4x56 row tile, b, g). Halo fp16 d-pair packed in
// XOR-swizzled LDS; ker read coalesced from global; fma_mix inner loop.
// Thread = (px-quad qi<56, d-quad dq<4): 4 px x 4 d outputs.
// ---------------------------------------------------------------------------
__global__ __launch_bounds__(256) void k3b_inv(
    const float* __restrict__ x, const unsigned short* __restrict__ ker,
    float* __restrict__ out, int b0)
{
    __shared__ unsigned xp2[8][10][64];   // [d-pair][yy][xx^sw], 20.5 KB

    const int t = threadIdx.x;
    const int h0 = blockIdx.x * 4;
    const int bl = blockIdx.y, b = b0 + bl;
    const int g = blockIdx.z;

    const float* xg = x + ((size_t)b * Cn + g * 16) * HWn;
    for (int e = t; e < 8 * 10 * 62; e += 256) {
        const int xx = e % 62;
        const int tmp = e / 62;
        const int yy = tmp % 10, dp = tmp / 10;
        const int hh = h0 + yy - 3, ww = xx - 3;
        unsigned pk = 0;
        if (hh >= 0 && hh < Hn && ww >= 0 && ww < Wn) {
            const float v0 = xg[(size_t)(dp * 2) * HWn + hh * Wn + ww];
            const float v1 = xg[(size_t)(dp * 2 + 1) * HWn + hh * Wn + ww];
            pk = (unsigned)f2h(v0) | ((unsigned)f2h(v1) << 16);
        }
        xp2[dp][yy][xx ^ ((yy & 3) << 2)] = pk;
    }
    __syncthreads();

    if (t >= 224) return;
    const int dq = t / 56, qi = t % 56;
    const int qy = qi / 14, qx = qi % 14;

    const unsigned short* kp = ker + ((size_t)(bl * 16 + g) * 49) * HWn
                               + (h0 + qy) * Wn + qx * 4;

    float acc[4][4];   // [dd][p], d = dq*4+dd
    #pragma unroll
    for (int dd = 0; dd < 4; ++dd)
        #pragma unroll
        for (int p = 0; p < 4; ++p) acc[dd][p] = 0.f;

    #pragma unroll
    for (int i = 0; i < 7; ++i) {
        const int yy = qy + i;
        const int sw = (yy & 3) << 2;
        unsigned xr0[12], xr1[12];
        #pragma unroll
        for (int u = 0; u < 3; ++u) {
            *(uint4*)&xr0[u * 4] = *(const uint4*)&xp2[dq * 2][yy][(qx * 4 + u * 4) ^ sw];
            *(uint4*)&xr1[u * 4] = *(const uint4*)&xp2[dq * 2 + 1][yy][(qx * 4 + u * 4) ^ sw];
        }
        #pragma unroll
        for (int j = 0; j < 7; ++j) {
            const ushort4 k4 = *(const ushort4*)&kp[(size_t)(i * 7 + j) * HWn];
            const unsigned short* kk = (const unsigned short*)&k4;
            #pragma unroll
            for (int p = 0; p < 4; ++p) {
                const float kf = h2f(kk[p]);
                const __half2 x0 = *(const __half2*)&xr0[j + p];
                const __half2 x1 = *(const __half2*)&xr1[j + p];
                acc[0][p] += __half2float(x0.x) * kf;
                acc[1][p] += __half2float(x0.y) * kf;
                acc[2][p] += __half2float(x1.x) * kf;
                acc[3][p] += __half2float(x1.y) * kf;
            }
        }
    }

    float* op = out + ((size_t)(b * Cn + g * 16 + dq * 4)) * HWn
                + (h0 + qy) * Wn + qx * 4;
    #pragma unroll
    for (int dd = 0; dd < 4; ++dd)
        *(float4*)(op + (size_t)dd * HWn) =
            make_float4(acc[dd][0], acc[dd][1], acc[dd][2], acc[dd][3]);
}

// ---------------------------------------------------------------------------
extern "C" void kernel_launch(void* const* d_in, const int* in_sizes, int n_in,
                              void* d_out, int out_size, void* d_ws, size_t ws_size,
                              hipStream_t stream)
{
    const float* x     = (const float*)d_in[0];
    const float* w1    = (const float*)d_in[1];
    // d_in[2] = b1: cancels exactly under training-mode BN
    const float* gamma = (const float*)d_in[3];
    const float* beta  = (const float*)d_in[4];
    const float* w2    = (const float*)d_in[5];
    const float* b2    = (const float*)d_in[6];
    float* out = (float*)d_out;
    char*  ws  = (char*)d_ws;

    if (ws_size < KER_OFF + KERB) return;   // fail loudly

    float* rT           = (float*)(ws + RT_OFF);
    float* part         = (float*)(ws + PART_OFF);
    float* part2        = (float*)(ws + PART2_OFF);
    float* ab           = (float*)(ws + AB_OFF);
    unsigned short* w1h = (unsigned short*)(ws + W1H_OFF);
    unsigned short* w1l = (unsigned short*)(ws + W1L_OFF);
    unsigned short* w2h = (unsigned short*)(ws + W2H_OFF);
    unsigned short* w2l = (unsigned short*)(ws + W2L_OFF);
    unsigned short* ker = (unsigned short*)(ws + KER_OFF);

    // largest chunk (in b's) whose ker buffer fits the workspace
    int c = 16;
    while (c > 1 && KER_OFF + KERB * (size_t)c > ws_size) c >>= 1;

    k0_prep<<<(64 * 256 + 16 * 64 * 64) / 256, 256, 0, stream>>>(
        w1, w2, w1h, w1l, w2h, w2l);
    k1_reduce<<<K1B, 256, 0, stream>>>(x, w1h, w1l, rT, part);
    k2a_fold<<<16, 128, 0, stream>>>(part, part2);
    k2_stats<<<1, 128, 0, stream>>>(part2, gamma, beta, ab);

    for (int b0 = 0; b0 < 16; b0 += c) {
        k3a_span<<<dim3(49, c, 2), 256, 0, stream>>>(rT, ab, w2h, w2l, b2, ker, b0);
        k3b_inv<<<dim3(14, c, 16), 256, 0, stream>>>(x, ker, out, b0);
    }
}

// Round 9
// 252.998 us; speedup vs baseline: 1.3866x; 1.3866x over previous
//
#include <hip/hip_runtime.h>
#include <hip/hip_fp16.h>

// Involution (B=16,C=256,H=W=56,K=7,G=16,CR=64).
// R8: latency-chain attack.
//  k1  : barrier-free MFMA reduce GEMM (per-lane direct A-frag loads + in-reg
//        split; no LDS staging). rT fp32 + BN partials.
//  k3a : span GEMM, 1 g per block (grid 16g x 49px x 16b), w2 prefetched
//        before barrier, D -> LDS [tap][px] -> coalesced uint4 ker stores.
//  k3b : involution, ker row i+1 register-prefetched under row i's FMAs.

namespace {
constexpr int Bn = 16, Cn = 256, Hn = 56, Wn = 56, Gn = 16, CRn = 64;
constexpr int HWn = Hn * Wn;          // 3136
constexpr int NPIX = Bn * HWn;        // 50176
constexpr int K1B = NPIX / 64;        // 784
constexpr float EPSc = 1e-5f;

constexpr size_t RT_OFF    = 0;                                 // fp32 [NPIX][64]
constexpr size_t PART_OFF  = RT_OFF + (size_t)NPIX * 64 * 4;    // fp32 [784][128]
constexpr size_t PART2_OFF = PART_OFF + (size_t)K1B * 128 * 4;  // fp32 [16][128]
constexpr size_t AB_OFF    = PART2_OFF + 16 * 128 * 4;          // fp32 [128]
constexpr size_t W1H_OFF   = AB_OFF + 512;                      // u16 [64][256]
constexpr size_t W1L_OFF   = W1H_OFF + (size_t)64 * 256 * 2;
constexpr size_t W2H_OFF   = W1L_OFF + (size_t)64 * 256 * 2;    // u16 [16][64][64]
constexpr size_t W2L_OFF   = W2H_OFF + (size_t)16 * 64 * 64 * 2;
constexpr size_t KER_OFF   = W2L_OFF + (size_t)16 * 64 * 64 * 2;
constexpr size_t KERB      = (size_t)16 * 49 * HWn * 2;         // per-b 4.92 MB
} // namespace

using f32x4  = __attribute__((ext_vector_type(4))) float;
using bf16x8 = __attribute__((ext_vector_type(8))) short;

__device__ __forceinline__ unsigned short f2bf(float f) {   // RNE fp32->bf16
    unsigned u = __float_as_uint(f);
    return (unsigned short)((u + 0x7fffu + ((u >> 16) & 1u)) >> 16);
}
__device__ __forceinline__ float bf2f(unsigned short h) {
    return __uint_as_float(((unsigned)h) << 16);
}
__device__ __forceinline__ void split2(float v, unsigned short& h, unsigned short& l) {
    h = f2bf(v);
    l = f2bf(v - bf2f(h));
}
__device__ __forceinline__ unsigned short f2h(float f) {
    __half h = __float2half(f);
    return *reinterpret_cast<unsigned short*>(&h);
}
__device__ __forceinline__ float h2f(unsigned short u) {
    __half h = *reinterpret_cast<__half*>(&u);
    return __half2float(h);
}
__device__ __forceinline__ f32x4 MFMA(bf16x8 a, bf16x8 b, f32x4 c) {
    return __builtin_amdgcn_mfma_f32_16x16x32_bf16(a, b, c, 0, 0, 0);
}

// ---------------------------------------------------------------------------
// K0: w1 -> bf16 hi/lo [o][c]; w2 -> bf16 hi/lo [g][tap(64,zero-pad)][cr]
// ---------------------------------------------------------------------------
__global__ __launch_bounds__(256) void k0_prep(
    const float* __restrict__ w1, const float* __restrict__ w2,
    unsigned short* __restrict__ w1h, unsigned short* __restrict__ w1l,
    unsigned short* __restrict__ w2h, unsigned short* __restrict__ w2l)
{
    const int i = blockIdx.x * 256 + threadIdx.x;
    if (i < 64 * 256) {
        unsigned short h, l;
        split2(w1[i], h, l);
        w1h[i] = h; w1l[i] = l;
    }
    const int j = i - 64 * 256;
    if (j >= 0 && j < 16 * 64 * 64) {
        const int cr = j & 63, tap = (j >> 6) & 63, g = j >> 12;
        const float v = (tap < 49) ? w2[(size_t)(tap * Gn + g) * CRn + cr] : 0.f;
        unsigned short h, l;
        split2(v, h, l);
        w2h[j] = h; w2l[j] = l;
    }
}

// ---------------------------------------------------------------------------
// K1 v3: barrier-free. Wave m-tile = 16 px. Lane (lm,lq) loads its A-frag
// (8 strided x floats, c = ks*32+lq*8..+8) directly, splits in registers.
// D: col o = n*16+lm, row px = wv*16 + lq*4 + i.
// ---------------------------------------------------------------------------
__global__ __launch_bounds__(256) void k1_reduce(
    const float* __restrict__ x,
    const unsigned short* __restrict__ w1h, const unsigned short* __restrict__ w1l,
    float* __restrict__ rT, float* __restrict__ part)
{
    __shared__ float wps[4][64], wpq[4][64];

    const int t = threadIdx.x;
    const int wv = t >> 6, l = t & 63, lm = l & 15, lq = l >> 4;
    const int blk = blockIdx.x;
    const int b = blk / 49;
    const int hw = (blk - b * 49) * 64 + wv * 16 + lm;   // this lane's px row
    const float* xb = x + (size_t)b * Cn * HWn + hw;

    f32x4 acc[4];
    #pragma unroll
    for (int n = 0; n < 4; ++n) acc[n] = f32x4{0.f, 0.f, 0.f, 0.f};

    for (int ks = 0; ks < 8; ++ks) {                     // 32-c K-steps
        float xv[8];
        #pragma unroll
        for (int j = 0; j < 8; ++j)
            xv[j] = xb[(size_t)(ks * 32 + lq * 8 + j) * HWn];
        bf16x8 ah, al;
        #pragma unroll
        for (int j = 0; j < 8; ++j) {
            unsigned short h, lo;
            split2(xv[j], h, lo);
            ah[j] = (short)h; al[j] = (short)lo;
        }
        #pragma unroll
        for (int n = 0; n < 4; ++n) {
            const size_t wo = (size_t)(n * 16 + lm) * 256 + ks * 32 + lq * 8;
            const bf16x8 bh = *(const bf16x8*)(w1h + wo);
            const bf16x8 bl = *(const bf16x8*)(w1l + wo);
            acc[n] = MFMA(al, bh, acc[n]);
            acc[n] = MFMA(ah, bl, acc[n]);
            acc[n] = MFMA(ah, bh, acc[n]);
        }
    }

    const int px0 = blk * 64;
    float s[4] = {0.f, 0.f, 0.f, 0.f}, q[4] = {0.f, 0.f, 0.f, 0.f};
    #pragma unroll
    for (int n = 0; n < 4; ++n)
        #pragma unroll
        for (int i = 0; i < 4; ++i) {
            const float v = acc[n][i];
            const int px = px0 + wv * 16 + lq * 4 + i;
            rT[(size_t)px * 64 + n * 16 + lm] = v;
            s[n] += v;
            q[n] += v * v;
        }
    #pragma unroll
    for (int n = 0; n < 4; ++n) {
        s[n] += __shfl_xor(s[n], 16, 64); s[n] += __shfl_xor(s[n], 32, 64);
        q[n] += __shfl_xor(q[n], 16, 64); q[n] += __shfl_xor(q[n], 32, 64);
        if (lq == 0) { wps[wv][n * 16 + lm] = s[n]; wpq[wv][n * 16 + lm] = q[n]; }
    }
    __syncthreads();
    if (t < 128) {
        const int ch = t >> 1;
        float v;
        if (t & 1) v = (wpq[0][ch] + wpq[1][ch]) + (wpq[2][ch] + wpq[3][ch]);
        else       v = (wps[0][ch] + wps[1][ch]) + (wps[2][ch] + wps[3][ch]);
        part[(size_t)blk * 128 + t] = v;
    }
}

// ---------------------------------------------------------------------------
__global__ __launch_bounds__(128) void k2a_fold(
    const float* __restrict__ part, float* __restrict__ part2)
{
    const int t = threadIdx.x, j = blockIdx.x;
    float s = 0.f;
    for (int c = 0; c < K1B / 16; ++c)
        s += part[(size_t)(j * (K1B / 16) + c) * 128 + t];
    part2[(size_t)j * 128 + t] = s;
}

__global__ __launch_bounds__(128) void k2_stats(
    const float* __restrict__ part2, const float* __restrict__ gamma,
    const float* __restrict__ beta, float* __restrict__ ab)
{
    const int t = threadIdx.x;
    float s = 0.f;
    #pragma unroll
    for (int j = 0; j < 16; ++j) s += part2[(size_t)j * 128 + t];
    __shared__ float L[128];
    L[t] = s;
    __syncthreads();
    if (t < 64) {
        const float inv = 1.0f / (float)NPIX;
        const float mean = L[2 * t] * inv;
        const float var = L[2 * t + 1] * inv - mean * mean;
        const float A = gamma[t] * rsqrtf(var + EPSc);
        ab[t] = A;
        ab[64 + t] = beta[t] - mean * A;
    }
}

// ---------------------------------------------------------------------------
// K3a v2: one g per block. grid (16 g, 49 px-tile, c b). A = w2 (row=tap,
// prefetched pre-barrier), B = r (col=px, BN+ReLU+split staged in swizzled
// LDS). D -> kst[tap][px] LDS bounce -> coalesced uint4 ker stores.
// ---------------------------------------------------------------------------
__global__ __launch_bounds__(256) void k3a_span(
    const float* __restrict__ rT, const float* __restrict__ ab,
    const unsigned short* __restrict__ w2h, const unsigned short* __restrict__ w2l,
    const float* __restrict__ b2, unsigned short* __restrict__ ker, int b0)
{
    __shared__ unsigned xsh[64][36];
    __shared__ unsigned xsl[64][36];
    __shared__ unsigned short kst[64][72];   // row stride 144B (16B multiple)

    const int t = threadIdx.x;
    const int wv = t >> 6, l = t & 63, lm = l & 15, lq = l >> 4;
    const int g = blockIdx.x;
    const int px0 = blockIdx.y * 64;
    const int bl = blockIdx.z, b = b0 + bl;

    // prefetch A-frags (w2, row tap = wv*16+lm) + bias — off critical path
    bf16x8 a_h[2], a_l[2];
    #pragma unroll
    for (int ks = 0; ks < 2; ++ks) {
        const size_t wo = (size_t)(g * 64 + wv * 16 + lm) * 64 + ks * 32 + lq * 8;
        a_h[ks] = *(const bf16x8*)(w2h + wo);
        a_l[ks] = *(const bf16x8*)(w2l + wo);
    }
    float bia[4];
    #pragma unroll
    for (int i = 0; i < 4; ++i) {
        const int tap = wv * 16 + lq * 4 + i;
        bia[i] = (tap < 49) ? b2[tap * Gn + g] : 0.f;
    }

    // stage rT tile 64px x 64cr with BN+ReLU+split (float4 loads)
    #pragma unroll
    for (int it = 0; it < 4; ++it) {
        const int e = it * 256 + t;               // float4 id
        const int c4 = e & 15, pxl = e >> 4;
        const float4 v = *(const float4*)&rT[((size_t)b * HWn + px0 + pxl) * 64 + c4 * 4];
        float r[4] = {v.x, v.y, v.z, v.w};
        unsigned short h[4], lo[4];
        #pragma unroll
        for (int k = 0; k < 4; ++k) {
            const int cr = c4 * 4 + k;
            const float rv = fmaxf(ab[cr] * r[k] + ab[64 + cr], 0.f);
            split2(rv, h[k], lo[k]);
        }
        const int sw = (pxl & 7) << 2;
        xsh[pxl][(c4 * 2) ^ sw]     = (unsigned)h[0] | ((unsigned)h[1] << 16);
        xsh[pxl][(c4 * 2 + 1) ^ sw] = (unsigned)h[2] | ((unsigned)h[3] << 16);
        xsl[pxl][(c4 * 2) ^ sw]     = (unsigned)lo[0] | ((unsigned)lo[1] << 16);
        xsl[pxl][(c4 * 2 + 1) ^ sw] = (unsigned)lo[2] | ((unsigned)lo[3] << 16);
    }
    __syncthreads();

    // GEMM: this wave = 16 taps x 64 px (4 n-tiles), K=64
    f32x4 acc[4];
    #pragma unroll
    for (int n = 0; n < 4; ++n) acc[n] = f32x4{0.f, 0.f, 0.f, 0.f};
    #pragma unroll
    for (int n = 0; n < 4; ++n) {
        const int pxl = n * 16 + lm;
        #pragma unroll
        for (int ks = 0; ks < 2; ++ks) {
            const int base = (ks * 16 + lq * 4) ^ ((pxl & 7) << 2);
            const bf16x8 bh  = *(const bf16x8*)&xsh[pxl][base];
            const bf16x8 blo = *(const bf16x8*)&xsl[pxl][base];
            acc[n] = MFMA(a_l[ks], bh,  acc[n]);
            acc[n] = MFMA(a_h[ks], blo, acc[n]);
            acc[n] = MFMA(a_h[ks], bh,  acc[n]);
        }
    }

    // D -> kst: row tap = wv*16+lq*4+i, col px-local = n*16+lm
    #pragma unroll
    for (int n = 0; n < 4; ++n)
        #pragma unroll
        for (int i = 0; i < 4; ++i)
            kst[wv * 16 + lq * 4 + i][n * 16 + lm] = f2h(acc[n][i] + bia[i]);
    __syncthreads();

    // coalesced ker stores: 49 rows x 128B
    unsigned short* kg = ker + ((size_t)(bl * 16 + g) * 49) * HWn + px0;
    for (int idx = t; idx < 49 * 8; idx += 256) {
        const int row = idx >> 3, c8 = (idx & 7) * 8;
        *(uint4*)&kg[(size_t)row * HWn + c8] = *(const uint4*)&kst[row][c8];
    }
}

// ---------------------------------------------------------------------------
// K3b: involution. Block = (4x56 rows, b, g). fp16 d-pair halo in swizzled
// LDS; ker row i+1 register-prefetched under row i's FMAs (fma_mix inner).
// ---------------------------------------------------------------------------
__global__ __launch_bounds__(256) void k3b_inv(
    const float* __restrict__ x, const unsigned short* __restrict__ ker,
    float* __restrict__ out, int b0)
{
    __shared__ unsigned xp2[8][10][64];   // [d-pair][yy][xx^sw], 20.5 KB

    const int t = threadIdx.x;
    const int h0 = blockIdx.x * 4;
    const int bl = blockIdx.y, b = b0 + bl;
    const int g = blockIdx.z;

    const float* xg = x + ((size_t)b * Cn + g * 16) * HWn;
    for (int e = t; e < 8 * 10 * 62; e += 256) {
        const int xx = e % 62;
        const int tmp = e / 62;
        const int yy = tmp % 10, dp = tmp / 10;
        const int hh = h0 + yy - 3, ww = xx - 3;
        unsigned pk = 0;
        if (hh >= 0 && hh < Hn && ww >= 0 && ww < Wn) {
            const float v0 = xg[(size_t)(dp * 2) * HWn + hh * Wn + ww];
            const float v1 = xg[(size_t)(dp * 2 + 1) * HWn + hh * Wn + ww];
            pk = (unsigned)f2h(v0) | ((unsigned)f2h(v1) << 16);
        }
        xp2[dp][yy][xx ^ ((yy & 3) << 2)] = pk;
    }
    __syncthreads();

    if (t >= 224) return;
    const int dq = t / 56, qi = t % 56;
    const int qy = qi / 14, qx = qi % 14;

    const unsigned short* kp = ker + ((size_t)(bl * 16 + g) * 49) * HWn
                               + (h0 + qy) * Wn + qx * 4;

    // preload ker row 0
    ushort4 kA[7], kB[7];
    #pragma unroll
    for (int j = 0; j < 7; ++j) kA[j] = *(const ushort4*)&kp[(size_t)j * HWn];

    float acc[4][4];
    #pragma unroll
    for (int dd = 0; dd < 4; ++dd)
        #pragma unroll
        for (int p = 0; p < 4; ++p) acc[dd][p] = 0.f;

    #pragma unroll
    for (int i = 0; i < 7; ++i) {
        const int yy = qy + i;
        const int sw = (yy & 3) << 2;
        unsigned xr0[12], xr1[12];
        #pragma unroll
        for (int u = 0; u < 3; ++u) {
            *(uint4*)&xr0[u * 4] = *(const uint4*)&xp2[dq * 2][yy][(qx * 4 + u * 4) ^ sw];
            *(uint4*)&xr1[u * 4] = *(const uint4*)&xp2[dq * 2 + 1][yy][(qx * 4 + u * 4) ^ sw];
        }
        if (i < 6) {                       // prefetch next ker row
            #pragma unroll
            for (int j = 0; j < 7; ++j)
                kB[j] = *(const ushort4*)&kp[(size_t)((i + 1) * 7 + j) * HWn];
        }
        #pragma unroll
        for (int j = 0; j < 7; ++j) {
            const unsigned short* kk = (const unsigned short*)&kA[j];
            #pragma unroll
            for (int p = 0; p < 4; ++p) {
                const float kf = h2f(kk[p]);
                const __half2 x0 = *(const __half2*)&xr0[j + p];
                const __half2 x1 = *(const __half2*)&xr1[j + p];
                acc[0][p] += __half2float(x0.x) * kf;
                acc[1][p] += __half2float(x0.y) * kf;
                acc[2][p] += __half2float(x1.x) * kf;
                acc[3][p] += __half2float(x1.y) * kf;
            }
        }
        #pragma unroll
        for (int j = 0; j < 7; ++j) kA[j] = kB[j];
    }

    float* op = out + ((size_t)(b * Cn + g * 16 + dq * 4)) * HWn
                + (h0 + qy) * Wn + qx * 4;
    #pragma unroll
    for (int dd = 0; dd < 4; ++dd)
        *(float4*)(op + (size_t)dd * HWn) =
            make_float4(acc[dd][0], acc[dd][1], acc[dd][2], acc[dd][3]);
}

// ---------------------------------------------------------------------------
extern "C" void kernel_launch(void* const* d_in, const int* in_sizes, int n_in,
                              void* d_out, int out_size, void* d_ws, size_t ws_size,
                              hipStream_t stream)
{
    const float* x     = (const float*)d_in[0];
    const float* w1    = (const float*)d_in[1];
    // d_in[2] = b1: cancels exactly under training-mode BN
    const float* gamma = (const float*)d_in[3];
    const float* beta  = (const float*)d_in[4];
    const float* w2    = (const float*)d_in[5];
    const float* b2    = (const float*)d_in[6];
    float* out = (float*)d_out;
    char*  ws  = (char*)d_ws;

    if (ws_size < KER_OFF + KERB) return;   // fail loudly

    float* rT           = (float*)(ws + RT_OFF);
    float* part         = (float*)(ws + PART_OFF);
    float* part2        = (float*)(ws + PART2_OFF);
    float* ab           = (float*)(ws + AB_OFF);
    unsigned short* w1h = (unsigned short*)(ws + W1H_OFF);
    unsigned short* w1l = (unsigned short*)(ws + W1L_OFF);
    unsigned short* w2h = (unsigned short*)(ws + W2H_OFF);
    unsigned short* w2l = (unsigned short*)(ws + W2L_OFF);
    unsigned short* ker = (unsigned short*)(ws + KER_OFF);

    int c = 16;
    while (c > 1 && KER_OFF + KERB * (size_t)c > ws_size) c >>= 1;

    k0_prep<<<(64 * 256 + 16 * 64 * 64 + 255) / 256, 256, 0, stream>>>(
        w1, w2, w1h, w1l, w2h, w2l);
    k1_reduce<<<K1B, 256, 0, stream>>>(x, w1h, w1l, rT, part);
    k2a_fold<<<16, 128, 0, stream>>>(part, part2);
    k2_stats<<<1, 128, 0, stream>>>(part2, gamma, beta, ab);

    for (int b0 = 0; b0 < 16; b0 += c) {
        k3a_span<<<dim3(16, 49, c), 256, 0, stream>>>(rT, ab, w2h, w2l, b2, ker, b0);
        k3b_inv<<<dim3(14, c, 16), 256, 0, stream>>>(x, ker, out, b0);
    }
}